// Round 9
// baseline (201.659 us; speedup 1.0000x reference)
//
#include <hip/hip_runtime.h>

// phase modulation, real-part output: out = x_r*cos(2*pi*p) - x_i*sin(2*pi*p)
// inside the centered 256x256 window; out = x_r elsewhere.
// R7 evidence: latency-bound (HBM 31%, VALU 19%, occ 66%). Fix: 16 elem/thread
// for 4x MLP + nontemporal stores so output doesn't evict L3-resident inputs.
// R8: __builtin_nontemporal_store needs a NATIVE vector type, not HIP float4.

#define TWO_PI 6.283185307179586f

constexpr int M = 512;       // spatial dim of x
constexpr int N = 256;       // spatial dim of phase
constexpr int START = 128;   // (M - N) / 2
constexpr int CH = 9;        // oc * ic

typedef float floatx4 __attribute__((ext_vector_type(4)));  // native vec for nt-store

__device__ __forceinline__ float4 mod4(float4 r, float4 im, float4 p) {
    float s0, c0, s1, c1, s2, c2, s3, c3;
    sincosf(TWO_PI * p.x, &s0, &c0);
    sincosf(TWO_PI * p.y, &s1, &c1);
    sincosf(TWO_PI * p.z, &s2, &c2);
    sincosf(TWO_PI * p.w, &s3, &c3);
    float4 o;
    o.x = r.x * c0 - im.x * s0;
    o.y = r.y * c1 - im.y * s1;
    o.z = r.z * c2 - im.z * s2;
    o.w = r.w * c3 - im.w * s3;
    return o;
}

__device__ __forceinline__ void nt_store4(float* dst, float4 v) {
    floatx4 nv;
    nv.x = v.x; nv.y = v.y; nv.z = v.z; nv.w = v.w;
    __builtin_nontemporal_store(nv, reinterpret_cast<floatx4*>(dst));
}

// ---- mode A: out is n float32 = real part; 16 elems (4 x float4) per thread ----
__global__ __launch_bounds__(256) void phase_mod_real16(
    const float* __restrict__ xr,
    const float* __restrict__ xi,
    const float* __restrict__ phase,
    float* __restrict__ out,
    int nthreads)
{
    int t = blockIdx.x * blockDim.x + threadIdx.x;
    if (t >= nthreads) return;

    long e = (long)t * 16;                // 16 consecutive cols, same row (16 | 512)
    int col     = (int)(e & (M - 1));
    int rowflat = (int)(e >> 9);
    int row     = rowflat & (M - 1);

    const float4* pr = reinterpret_cast<const float4*>(xr + e);
    float4 r0 = pr[0];                    // 4 independent loads in flight
    float4 r1 = pr[1];
    float4 r2 = pr[2];
    float4 r3 = pr[3];

    // 16-col group entirely inside or outside (128 and 384 are multiples of 16)
    bool inside = ((unsigned)(row - START) < (unsigned)N) &&
                  ((unsigned)(col - START) < (unsigned)N);
    if (inside) {
        int chan = (rowflat >> 9) % CH;
        long pidx = (long)chan * (N * N) + (long)(row - START) * N + (col - START);
        const float4* pp = reinterpret_cast<const float4*>(phase + pidx);
        const float4* pi = reinterpret_cast<const float4*>(xi + e);
        float4 p0 = pp[0], p1 = pp[1], p2 = pp[2], p3 = pp[3];
        float4 i0 = pi[0], i1 = pi[1], i2 = pi[2], i3 = pi[3];
        r0 = mod4(r0, i0, p0);
        r1 = mod4(r1, i1, p1);
        r2 = mod4(r2, i2, p2);
        r3 = mod4(r3, i3, p3);
    }

    nt_store4(out + e,      r0);   // output never re-read: don't pollute L3
    nt_store4(out + e + 4,  r1);
    nt_store4(out + e + 8,  r2);
    nt_store4(out + e + 12, r3);
}

// ---- mode B (defensive, if out_size >= 2n): interleaved complex64, 4 elems/thread ----
__global__ __launch_bounds__(256) void phase_mod_cplx_kernel(
    const float* __restrict__ xr,
    const float* __restrict__ xi,
    const float* __restrict__ phase,
    float* __restrict__ out,
    int nvec4)
{
    int t = blockIdx.x * blockDim.x + threadIdx.x;
    if (t >= nvec4) return;
    long e = (long)t * 4;
    int col     = (int)(e & (M - 1));
    int rowflat = (int)(e >> 9);
    int row     = rowflat & (M - 1);

    float4 r  = *reinterpret_cast<const float4*>(xr + e);
    float4 im = *reinterpret_cast<const float4*>(xi + e);
    float4 o0 = make_float4(r.x, im.x, r.y, im.y);
    float4 o1 = make_float4(r.z, im.z, r.w, im.w);

    bool inside = ((unsigned)(row - START) < (unsigned)N) &&
                  ((unsigned)(col - START) < (unsigned)N);
    if (inside) {
        int chan = (rowflat >> 9) % CH;
        long pidx = (long)chan * (N * N) + (long)(row - START) * N + (col - START);
        float4 p = *reinterpret_cast<const float4*>(phase + pidx);
        float s0, c0, s1, c1, s2, c2, s3, c3;
        sincosf(TWO_PI * p.x, &s0, &c0);
        sincosf(TWO_PI * p.y, &s1, &c1);
        sincosf(TWO_PI * p.z, &s2, &c2);
        sincosf(TWO_PI * p.w, &s3, &c3);
        o0.x = r.x * c0 - im.x * s0;  o0.y = r.x * s0 + im.x * c0;
        o0.z = r.y * c1 - im.y * s1;  o0.w = r.y * s1 + im.y * c1;
        o1.x = r.z * c2 - im.z * s2;  o1.y = r.z * s2 + im.z * c2;
        o1.z = r.w * c3 - im.w * s3;  o1.w = r.w * s3 + im.w * c3;
    }
    *reinterpret_cast<float4*>(out + 2 * e)     = o0;
    *reinterpret_cast<float4*>(out + 2 * e + 4) = o1;
}

extern "C" void kernel_launch(void* const* d_in, const int* in_sizes, int n_in,
                              void* d_out, int out_size, void* d_ws, size_t ws_size,
                              hipStream_t stream) {
    const float* xr    = (const float*)d_in[0];
    const float* xi    = (const float*)d_in[1];
    const float* phase = (const float*)d_in[2];
    float* out = (float*)d_out;

    long n = in_sizes[0];            // 18,874,368
    int block = 256;

    if ((long)out_size >= 2 * n) {
        int nvec4 = (int)(n / 4);
        int grid = (nvec4 + block - 1) / block;
        phase_mod_cplx_kernel<<<grid, block, 0, stream>>>(xr, xi, phase, out, nvec4);
    } else {
        int nthreads = (int)(n / 16);               // 1,179,648
        int grid = (nthreads + block - 1) / block;  // 4,608 blocks
        phase_mod_real16<<<grid, block, 0, stream>>>(xr, xi, phase, out, nthreads);
    }
}

// Round 10
// 179.897 us; speedup vs baseline: 1.1210x; 1.1210x over previous
//
#include <hip/hip_runtime.h>

// phase modulation, real-part output: out = x_r*cos(2*pi*p) - x_i*sin(2*pi*p)
// inside centered 256x256 window; out = x_r elsewhere.
// R7: latency-bound (HBM 31%, VALU 19%). R9: 16-contig-elem/thread broke lane
// coalescing -> partial-line nt writes, WRITE_SIZE +59%, 80us. R10 fix: keep
// 4x float4 MLP but CHUNK-STRIDED (each instruction wave-contiguous, 1KB/wave).

#define TWO_PI 6.283185307179586f

constexpr int M = 512;
constexpr int N = 256;
constexpr int START = 128;
constexpr int CH = 9;

typedef float floatx4 __attribute__((ext_vector_type(4)));

__device__ __forceinline__ float4 mod4(float4 r, float4 im, float4 p) {
    float s0, c0, s1, c1, s2, c2, s3, c3;
    sincosf(TWO_PI * p.x, &s0, &c0);
    sincosf(TWO_PI * p.y, &s1, &c1);
    sincosf(TWO_PI * p.z, &s2, &c2);
    sincosf(TWO_PI * p.w, &s3, &c3);
    float4 o;
    o.x = r.x * c0 - im.x * s0;
    o.y = r.y * c1 - im.y * s1;
    o.z = r.z * c2 - im.z * s2;
    o.w = r.w * c3 - im.w * s3;
    return o;
}

__device__ __forceinline__ void nt_store4(float* dst, float4 v) {
    floatx4 nv;
    nv.x = v.x; nv.y = v.y; nv.z = v.z; nv.w = v.w;
    __builtin_nontemporal_store(nv, reinterpret_cast<floatx4*>(dst));
}

// Block owns 4096 contiguous floats (8 rows). Chunk k: e = base + k*1024 + tid*4.
// col = (tid&127)*4 is chunk-invariant; chan is block-invariant (4096 | 512*512).
__global__ __launch_bounds__(256) void phase_mod_real_strided(
    const float* __restrict__ xr,
    const float* __restrict__ xi,
    const float* __restrict__ phase,
    float* __restrict__ out)
{
    const int tid = threadIdx.x;
    const long tile = (long)blockIdx.x * 4096;
    const long base = tile + (long)tid * 4;

    long e[4];
    float4 r[4];
    #pragma unroll
    for (int k = 0; k < 4; ++k) {
        e[k] = base + k * 1024;
        r[k] = *reinterpret_cast<const float4*>(xr + e[k]);   // 4 independent streams
    }

    const int col = (int)(base & (M - 1));                    // same for all chunks
    const bool colIn = (unsigned)(col - START) < (unsigned)N;
    const int chan = (int)((tile >> 18) % CH);                // image = 512*512 = 2^18

    int rowm[4];
    bool ins[4];
    #pragma unroll
    for (int k = 0; k < 4; ++k) {
        int row = (int)((e[k] >> 9) & (M - 1));
        rowm[k] = row - START;
        ins[k] = colIn && ((unsigned)rowm[k] < (unsigned)N);
    }

    float4 im[4], p[4];
    #pragma unroll
    for (int k = 0; k < 4; ++k) {
        if (ins[k]) {
            long pidx = (long)chan * (N * N) + (long)rowm[k] * N + (col - START);
            p[k]  = *reinterpret_cast<const float4*>(phase + pidx);
            im[k] = *reinterpret_cast<const float4*>(xi + e[k]);
        }
    }
    #pragma unroll
    for (int k = 0; k < 4; ++k) {
        if (ins[k]) r[k] = mod4(r[k], im[k], p[k]);
    }

    #pragma unroll
    for (int k = 0; k < 4; ++k) {
        nt_store4(out + e[k], r[k]);   // wave-contiguous full-line nt store
    }
}

// ---- mode B (defensive, if out_size >= 2n): interleaved complex64 ----
__global__ __launch_bounds__(256) void phase_mod_cplx_kernel(
    const float* __restrict__ xr,
    const float* __restrict__ xi,
    const float* __restrict__ phase,
    float* __restrict__ out,
    int nvec4)
{
    int t = blockIdx.x * blockDim.x + threadIdx.x;
    if (t >= nvec4) return;
    long e = (long)t * 4;
    int col     = (int)(e & (M - 1));
    int rowflat = (int)(e >> 9);
    int row     = rowflat & (M - 1);

    float4 r  = *reinterpret_cast<const float4*>(xr + e);
    float4 im = *reinterpret_cast<const float4*>(xi + e);
    float4 o0 = make_float4(r.x, im.x, r.y, im.y);
    float4 o1 = make_float4(r.z, im.z, r.w, im.w);

    bool inside = ((unsigned)(row - START) < (unsigned)N) &&
                  ((unsigned)(col - START) < (unsigned)N);
    if (inside) {
        int chan = (rowflat >> 9) % CH;
        long pidx = (long)chan * (N * N) + (long)(row - START) * N + (col - START);
        float4 p = *reinterpret_cast<const float4*>(phase + pidx);
        float s0, c0, s1, c1, s2, c2, s3, c3;
        sincosf(TWO_PI * p.x, &s0, &c0);
        sincosf(TWO_PI * p.y, &s1, &c1);
        sincosf(TWO_PI * p.z, &s2, &c2);
        sincosf(TWO_PI * p.w, &s3, &c3);
        o0.x = r.x * c0 - im.x * s0;  o0.y = r.x * s0 + im.x * c0;
        o0.z = r.y * c1 - im.y * s1;  o0.w = r.y * s1 + im.y * c1;
        o1.x = r.z * c2 - im.z * s2;  o1.y = r.z * s2 + im.z * c2;
        o1.z = r.w * c3 - im.w * s3;  o1.w = r.w * s3 + im.w * c3;
    }
    *reinterpret_cast<float4*>(out + 2 * e)     = o0;
    *reinterpret_cast<float4*>(out + 2 * e + 4) = o1;
}

extern "C" void kernel_launch(void* const* d_in, const int* in_sizes, int n_in,
                              void* d_out, int out_size, void* d_ws, size_t ws_size,
                              hipStream_t stream) {
    const float* xr    = (const float*)d_in[0];
    const float* xi    = (const float*)d_in[1];
    const float* phase = (const float*)d_in[2];
    float* out = (float*)d_out;

    long n = in_sizes[0];            // 18,874,368
    int block = 256;

    if ((long)out_size >= 2 * n) {
        int nvec4 = (int)(n / 4);
        int grid = (nvec4 + block - 1) / block;
        phase_mod_cplx_kernel<<<grid, block, 0, stream>>>(xr, xi, phase, out, nvec4);
    } else {
        int grid = (int)(n / 4096);                 // 4,608 blocks, exact cover
        phase_mod_real_strided<<<grid, block, 0, stream>>>(xr, xi, phase, out);
    }
}